// Round 3
// baseline (1622.167 us; speedup 1.0000x reference)
//
#include <hip/hip_runtime.h>
#include <cstdint>

typedef unsigned short u16;
typedef __bf16  bf16x8 __attribute__((ext_vector_type(8)));
typedef float   f32x4  __attribute__((ext_vector_type(4)));

#define S_LEN 3072
#define DMODEL 1024

__device__ __forceinline__ float bf2f(u16 u){ return __uint_as_float(((unsigned)u) << 16); }
__device__ __forceinline__ u16 f2bf(float f){
    unsigned u = __float_as_uint(f);
    return (u16)((u + 0x7fffu + ((u >> 16) & 1u)) >> 16);
}
// mode-aware element fetch -> bf16 bits (mode 0: input already bf16; mode 1: fp32)
__device__ __forceinline__ u16 cvld(const void* p, long i, int mode){
    return mode ? f2bf(((const float*)p)[i]) : ((const u16*)p)[i];
}

// ---------------------------------------------------------------------------
// dtype sniffer: decides whether inputs are bf16 (flag=0) or fp32 (flag=1)
// by exponent-field statistics of the first 4096 u16 of `hidden` (N(0,1)).
// Also writes flag[1] = 0 (constant "bf16 mode" flag for ws-internal use).
// ---------------------------------------------------------------------------
__global__ void sniff_kernel(const u16* __restrict__ x, int* __restrict__ flag)
{
    __shared__ int r[256];
    int tid = threadIdx.x, w = 0;
    for (int j = tid; j < 4096; j += 256){
        int e = (x[j] >> 7) & 0xFF;
        if (e < 90 || e > 140) w++;     // bf16 N(0,1): ~0 hits; fp32-as-u16: ~50%
    }
    r[tid] = w; __syncthreads();
    for (int s = 128; s > 0; s >>= 1){ if (tid < s) r[tid] += r[tid + s]; __syncthreads(); }
    if (tid == 0){ flag[0] = (r[0] > 256) ? 1 : 0; flag[1] = 0; }
}

// ---------------------------------------------------------------------------
// NT GEMM: C[M,N] = A[M,K](row,lda,bf16) * B[N,K]^T(row,ldb,bf16) + bias
// m93-style staging (sync vector loads + ds_write_b128) for bulletproof
// correctness; 128x128 tile, BK=64, 4 waves, 4x4 mfma_f32_16x16x32_bf16.
// ---------------------------------------------------------------------------
template<bool RELU, bool SPLITN>
__global__ __launch_bounds__(256)
void gemm_nt(const u16* __restrict__ A, int lda,
             const u16* __restrict__ B, int ldb,
             u16* __restrict__ C, int ldc,
             const u16* __restrict__ bias,
             int K, int splitRows,
             long aBS, long bBS, long cBS)
{
    __shared__ __align__(16) u16 Abuf[128 * 64];
    __shared__ __align__(16) u16 Bbuf[128 * 64];
    const int tid  = threadIdx.x;
    const int lane = tid & 63, wid = tid >> 6;
    const int wm = wid >> 1, wn = wid & 1;
    const int quad = lane >> 4, lr = lane & 15;

    A += (long)blockIdx.z * aBS + (long)blockIdx.x * 128 * lda;
    B += (long)blockIdx.z * bBS + (long)blockIdx.y * 128 * ldb;

    f32x4 zero = {0.f, 0.f, 0.f, 0.f};
    f32x4 acc[4][4];
#pragma unroll
    for (int i = 0; i < 4; i++)
#pragma unroll
        for (int j = 0; j < 4; j++) acc[i][j] = zero;

    int um[4], ukq[4];
#pragma unroll
    for (int i = 0; i < 4; i++){
        int u = i * 256 + tid;
        um[i]  = u >> 3;       // row within 128-tile
        ukq[i] = u & 7;        // 16B unit within 64-wide K slab (linear m97 layout)
    }

    const int kTiles = K >> 6;
    for (int kt = 0; kt < kTiles; ++kt){
        const int k0 = kt << 6;
        bf16x8 av[4], bv[4];
#pragma unroll
        for (int i = 0; i < 4; i++)
            av[i] = *(const bf16x8*)(A + (long)um[i] * lda + k0 + ukq[i] * 8);
#pragma unroll
        for (int i = 0; i < 4; i++)
            bv[i] = *(const bf16x8*)(B + (long)um[i] * ldb + k0 + ukq[i] * 8);
        __syncthreads();   // previous iteration's ds_reads done
#pragma unroll
        for (int i = 0; i < 4; i++)
            *(bf16x8*)(Abuf + (i * 256 + tid) * 8) = av[i];
#pragma unroll
        for (int i = 0; i < 4; i++)
            *(bf16x8*)(Bbuf + (i * 256 + tid) * 8) = bv[i];
        __syncthreads();   // tile visible to all waves
#pragma unroll
        for (int ks = 0; ks < 2; ++ks){
            bf16x8 af[4], bfg[4];
#pragma unroll
            for (int t = 0; t < 4; t++){
                int m  = wm * 64 + t * 16 + lr;
                af[t]  = *(const bf16x8*)(Abuf + (m * 8 + ks * 4 + quad) * 8);
                int n  = wn * 64 + t * 16 + lr;
                bfg[t] = *(const bf16x8*)(Bbuf + (n * 8 + ks * 4 + quad) * 8);
            }
#pragma unroll
            for (int mt = 0; mt < 4; mt++)
#pragma unroll
                for (int nt = 0; nt < 4; nt++)
                    acc[mt][nt] = __builtin_amdgcn_mfma_f32_16x16x32_bf16(
                        af[mt], bfg[nt], acc[mt][nt], 0, 0, 0);
        }
    }

    const long cOff = (long)blockIdx.z * cBS;
    const int rowBase = blockIdx.x * 128 + wm * 64;
    const int colBase = blockIdx.y * 128 + wn * 64;
#pragma unroll
    for (int mt = 0; mt < 4; ++mt){
#pragma unroll
        for (int nt = 0; nt < 4; ++nt){
            const int col = colBase + nt * 16 + lr;
            float bv2 = bias ? bf2f(bias[col]) : 0.f;
#pragma unroll
            for (int r = 0; r < 4; r++){
                int row = rowBase + mt * 16 + quad * 4 + r;   // C/D: col=lane&15, row=quad*4+reg
                float v = acc[mt][nt][r] + bv2;
                if (RELU) v = fmaxf(v, 0.f);
                long idx;
                if (SPLITN) idx = ((long)(col >> 10) * splitRows + row) * DMODEL + (col & (DMODEL - 1));
                else        idx = (long)row * ldc + col;
                C[cOff + idx] = f2bf(v);
            }
        }
    }
}

// ---------------------------------------------------------------------------
// mode-aware tiled transpose: out[C,R] = in[R,C]^T (bf16 out), batched over z
// ---------------------------------------------------------------------------
__global__ __launch_bounds__(256)
void transpose_cvt(const int* __restrict__ flag, const void* __restrict__ in, long srcOff,
                   u16* __restrict__ out, int R, int C, long inB, long outB)
{
    __shared__ u16 t[32][34];
    const int mode = *flag;
    const long ib = srcOff + (long)blockIdx.z * inB;
    u16* op = out + (long)blockIdx.z * outB;
    int c0 = blockIdx.x * 32, r0 = blockIdx.y * 32;
    int tx = threadIdx.x, ty = threadIdx.y;
#pragma unroll
    for (int j = 0; j < 4; j++){
        int r = r0 + ty + j * 8;
        t[ty + j * 8][tx] = cvld(in, ib + (long)r * C + c0 + tx, mode);
    }
    __syncthreads();
#pragma unroll
    for (int j = 0; j < 4; j++){
        int c = c0 + ty + j * 8;
        op[(long)c * R + r0 + tx] = t[tx][ty + j * 8];
    }
}

__global__ __launch_bounds__(256)
void init_h(const int* __restrict__ flag, const void* __restrict__ hin,
            float* __restrict__ h, u16* __restrict__ hbf)
{
    const int mode = *flag;
    long i = (long)blockIdx.x * 256 + threadIdx.x;
    u16 u = cvld(hin, i, mode);
    h[i]   = bf2f(u);
    hbf[i] = u;
}

// bias arena layout (elements)
#define OFF_BQKV 0
#define OFF_BH   12288
#define OFF_BO   16384
#define OFF_BF1  20480
#define OFF_BF2  28672
#define OFF_G1   32768
#define OFF_B1N  36864
#define OFF_G2   40960
#define OFF_B2N  45056
#define OFF_WHD  49152
#define OFF_BHD  53248
#define BIAS_TOT 53252

__global__ __launch_bounds__(256)
void cvt_biases(const int* __restrict__ flag,
                const void* bq, const void* bk, const void* bv, const void* bh,
                const void* bo, const void* bf1, const void* bf2,
                const void* g1, const void* b1n, const void* g2, const void* b2n,
                const void* whd, const void* bhd, u16* __restrict__ A)
{
    int i = blockIdx.x * 256 + threadIdx.x;
    if (i >= BIAS_TOT) return;
    const int mode = *flag;
    u16 v;
    if (i < OFF_BH){
        int l = i / 3072, r = i % 3072;
        const void* p = (r < 1024) ? bq : (r < 2048) ? bk : bv;
        v = cvld(p, (long)l * 1024 + (r & 1023), mode);
    }
    else if (i < OFF_BO)  v = cvld(bh,  i - OFF_BH, mode);
    else if (i < OFF_BF1) v = cvld(bo,  i - OFF_BO, mode);
    else if (i < OFF_BF2) v = cvld(bf1, i - OFF_BF1, mode);
    else if (i < OFF_G1)  v = cvld(bf2, i - OFF_BF2, mode);
    else if (i < OFF_B1N) v = cvld(g1,  i - OFF_G1, mode);
    else if (i < OFF_G2)  v = cvld(b1n, i - OFF_B1N, mode);
    else if (i < OFF_B2N) v = cvld(g2,  i - OFF_G2, mode);
    else if (i < OFF_WHD) v = cvld(b2n, i - OFF_B2N, mode);
    else if (i < OFF_BHD) v = cvld(whd, i - OFF_WHD, mode);
    else                  v = cvld(bhd, i - OFF_BHD, mode);
    A[i] = v;
}

__device__ __forceinline__ float blockSum(float v, float* red){
    int lane = threadIdx.x & 63, wid = threadIdx.x >> 6;
#pragma unroll
    for (int o = 32; o > 0; o >>= 1) v += __shfl_down(v, o, 64);
    __syncthreads();
    if (lane == 0) red[wid] = v;
    __syncthreads();
    return red[0] + red[1] + red[2] + red[3];
}
__device__ __forceinline__ float blockMax(float v, float* red){
    int lane = threadIdx.x & 63, wid = threadIdx.x >> 6;
#pragma unroll
    for (int o = 32; o > 0; o >>= 1) v = fmaxf(v, __shfl_down(v, o, 64));
    __syncthreads();
    if (lane == 0) red[wid] = v;
    __syncthreads();
    return fmaxf(fmaxf(red[0], red[1]), fmaxf(red[2], red[3]));
}

// h = LN(h + x) * g + b ; fp32 h in place, bf16 copy out; x,g,b bf16
__global__ __launch_bounds__(256)
void ln_kernel(float* __restrict__ h, const u16* __restrict__ x,
               u16* __restrict__ hbf, const u16* __restrict__ g, const u16* __restrict__ b)
{
    __shared__ float red[4];
    long base = (long)blockIdx.x * DMODEL;
    int tid = threadIdx.x;
    float v[4];
    float s = 0.f;
#pragma unroll
    for (int j = 0; j < 4; j++){
        int c = tid + j * 256;
        float r = h[base + c] + bf2f(x[base + c]);
        v[j] = r; s += r;
    }
    float mu = blockSum(s, red) * (1.f / DMODEL);
    float s2 = 0.f;
#pragma unroll
    for (int j = 0; j < 4; j++){ float d = v[j] - mu; s2 += d * d; }
    float var = blockSum(s2, red) * (1.f / DMODEL);
    float inv = rsqrtf(var + 1e-5f);
#pragma unroll
    for (int j = 0; j < 4; j++){
        int c = tid + j * 256;
        float y = (v[j] - mu) * inv * bf2f(g[c]) + bf2f(b[c]);
        h[base + c]   = y;
        hbf[base + c] = f2bf(y);
    }
}

// in-place row softmax (bf16, row length S_LEN), scale 1/sqrt(DK)
__global__ __launch_bounds__(256)
void softmax_kernel(u16* __restrict__ P)
{
    __shared__ float red[4];
    u16* row = P + ((long)blockIdx.y * S_LEN + blockIdx.x) * S_LEN;
    int tid = threadIdx.x;
    const float scale = 0.0625f;    // 1/sqrt(256)
    float x[12];
    float m = -1e30f;
#pragma unroll
    for (int j = 0; j < 12; j++){
        x[j] = bf2f(row[tid + j * 256]) * scale;
        m = fmaxf(m, x[j]);
    }
    m = blockMax(m, red);
    float s = 0.f;
#pragma unroll
    for (int j = 0; j < 12; j++){ x[j] = __expf(x[j] - m); s += x[j]; }
    s = blockSum(s, red);
    float inv = 1.f / s;
#pragma unroll
    for (int j = 0; j < 12; j++) row[tid + j * 256] = f2bf(x[j] * inv);
}

__global__ __launch_bounds__(256)
void head_kernel(const int* __restrict__ flag, const float* __restrict__ h,
                 const u16* __restrict__ arena, const int* __restrict__ nePtr,
                 const int* __restrict__ naPtr, void* __restrict__ outp)
{
    __shared__ float red[4];
    int o = blockIdx.x;
    int ne = *nePtr, na = *naPtr;
    int widx, row;
    if (o < 3 * na){ widx = o / na; row = ne + o % na; }
    else           { widx = 3;      row = o - 3 * na; }
    int tid = threadIdx.x;
    const float* hr = h + (long)row * DMODEL;
    const u16*   w  = arena + OFF_WHD + widx * DMODEL;
    float s = 0.f;
#pragma unroll
    for (int j = 0; j < 4; j++){ int c = tid + j * 256; s += hr[c] * bf2f(w[c]); }
    s = blockSum(s, red);
    if (tid == 0){
        float r = s + bf2f(arena[OFF_BHD + widx]);
        if (*flag) ((float*)outp)[o] = r;
        else       ((u16*)outp)[o]   = f2bf(r);
    }
}

// ---------------------------------------------------------------------------
extern "C" void kernel_launch(void* const* d_in, const int* in_sizes, int n_in,
                              void* d_out, int out_size, void* d_ws, size_t ws_size,
                              hipStream_t stream)
{
    const void* hidden = d_in[0];
    const void* Wq  = d_in[1];  const void* bq  = d_in[2];
    const void* Wk  = d_in[3];  const void* bk  = d_in[4];
    const void* Wv  = d_in[5];  const void* bv  = d_in[6];
    const void* Wh  = d_in[7];  const void* bh  = d_in[8];
    const void* Wo  = d_in[9];  const void* bo  = d_in[10];
    const void* g1  = d_in[11]; const void* b1n = d_in[12];
    const void* g2  = d_in[13]; const void* b2n = d_in[14];
    const void* Wf1 = d_in[15]; const void* bf1 = d_in[16];
    const void* Wf2 = d_in[17]; const void* bf2 = d_in[18];
    const void* Whd = d_in[19]; const void* bhd = d_in[20];
    const int* nePtr = (const int*)d_in[21];
    const int* naPtr = (const int*)d_in[22];

    const long D = 1024, S = 3072, L = 4, DK = 256;

    char* ws = (char*)d_ws;
    size_t off = 0;
    auto alloc = [&](size_t bytes)->char*{
        char* p = ws + off;
        off = (off + bytes + 255) & ~(size_t)255;
        return p;
    };
    int*  flag  = (int*)alloc(256);
    u16*  barena= (u16*)alloc(BIAS_TOT * 2);
    u16*  WqkvT = (u16*)alloc(3 * D * D * 2);      // per-layer [WqT|WkT|WvT]
    u16*  WhT   = (u16*)alloc(D * D * 2);
    u16*  WoT   = (u16*)alloc(D * D * 2);
    u16*  Wf1T  = (u16*)alloc(2 * D * D * 2);
    u16*  Wf2T  = (u16*)alloc(2 * D * D * 2);
    float* h    = (float*)alloc(S * D * 4);
    u16*  hbf   = (u16*)alloc(S * D * 2);
    u16*  qkvh  = (u16*)alloc(3 * S * D * 2);      // [Qh;Kh;Vh]
    char* regionA = alloc(3 * S * D * 2);          // qkv -> later vhT|ctx
    u16*  tmpbf = (u16*)alloc(S * D * 2);
    size_t baseEnd = off;
    int HB = (ws_size >= baseEnd + (size_t)4 * S * S * 2 + 4096) ? 4 : 1;
    size_t regBbytes = (size_t)HB * S * S * 2;
    if (regBbytes < (size_t)S * 2 * D * 2) regBbytes = (size_t)S * 2 * D * 2;
    char* regionB = alloc(regBbytes);              // scores | ffn1

    u16* qkv     = (u16*)regionA;                  // dead after qkvh GEMM
    u16* vhT     = (u16*)regionA;                  // (D x S)
    u16* ctx     = (u16*)regionA + D * S;          // (S x D)
    u16* scoresP = (u16*)regionB;
    u16* ffn1    = (u16*)regionB;

    dim3 tb(32, 8);
    sniff_kernel<<<1, 256, 0, stream>>>((const u16*)hidden, flag);
    cvt_biases<<<(BIAS_TOT + 255) / 256, 256, 0, stream>>>(
        flag, bq, bk, bv, bh, bo, bf1, bf2, g1, b1n, g2, b2n, Whd, bhd, barena);
    init_h<<<(int)(S * D / 256), 256, 0, stream>>>(flag, hidden, h, hbf);

    for (int l = 0; l < L; ++l){
        transpose_cvt<<<dim3(32, 32, 1), tb, 0, stream>>>(flag, Wq, (long)l * D * D, WqkvT,             1024, 1024, 0, 0);
        transpose_cvt<<<dim3(32, 32, 1), tb, 0, stream>>>(flag, Wk, (long)l * D * D, WqkvT + D * D,     1024, 1024, 0, 0);
        transpose_cvt<<<dim3(32, 32, 1), tb, 0, stream>>>(flag, Wv, (long)l * D * D, WqkvT + 2 * D * D, 1024, 1024, 0, 0);
        transpose_cvt<<<dim3(8, 32, 4), tb, 0, stream>>>(flag, Wh, (long)l * 4 * D * DK, WhT, 1024, 256, D * DK, D * DK);
        transpose_cvt<<<dim3(32, 32, 1), tb, 0, stream>>>(flag, Wo, (long)l * D * D, WoT, 1024, 1024, 0, 0);
        transpose_cvt<<<dim3(64, 32, 1), tb, 0, stream>>>(flag, Wf1, (long)l * 2 * D * D, Wf1T, 1024, 2048, 0, 0);
        transpose_cvt<<<dim3(32, 64, 1), tb, 0, stream>>>(flag, Wf2, (long)l * 2 * D * D, Wf2T, 2048, 1024, 0, 0);

        // QKV: (S x 3072) -> stacked Q,K,V (each S x D)
        gemm_nt<false, true><<<dim3(24, 24, 1), 256, 0, stream>>>(
            hbf, 1024, WqkvT, 1024, qkv, 0,
            barena + OFF_BQKV + l * 3 * D, 1024, (int)S, 0, 0, 0);
        // Qh/Kh/Vh stacked (9216 x 1024)
        gemm_nt<false, false><<<dim3(72, 8, 1), 256, 0, stream>>>(
            qkv, 1024, WhT, 1024, qkvh, 1024,
            barena + OFF_BH + l * D, 1024, 0, 0, 0, 0);
        // Vh^T (D x S) — ws-internal bf16, flag+1 is constant 0
        transpose_cvt<<<dim3(32, 96, 1), tb, 0, stream>>>(flag + 1, qkvh, 2 * S * D, vhT, (int)S, (int)D, 0, 0);

        for (int h0 = 0; h0 < 4; h0 += HB){
            gemm_nt<false, false><<<dim3(24, 24, HB), 256, 0, stream>>>(
                qkvh + h0 * DK, 1024, qkvh + S * D + h0 * DK, 1024,
                scoresP, (int)S, nullptr, (int)DK, 0, DK, DK, (long)S * S);
            softmax_kernel<<<dim3(3072, HB, 1), 256, 0, stream>>>(scoresP);
            gemm_nt<false, false><<<dim3(24, 2, HB), 256, 0, stream>>>(
                scoresP, (int)S, vhT + (long)h0 * DK * S, (int)S,
                ctx + h0 * DK, 1024, nullptr, (int)S, 0,
                (long)S * S, (long)DK * S, DK);
        }
        // attn_out -> tmpbf
        gemm_nt<false, false><<<dim3(24, 8, 1), 256, 0, stream>>>(
            ctx, 1024, WoT, 1024, tmpbf, 1024,
            barena + OFF_BO + l * D, 1024, 0, 0, 0, 0);
        ln_kernel<<<3072, 256, 0, stream>>>(h, tmpbf, hbf, barena + OFF_G1 + l * D, barena + OFF_B1N + l * D);
        // FFN1 (+ReLU) — overwrites scoresP (dead)
        gemm_nt<true, false><<<dim3(24, 16, 1), 256, 0, stream>>>(
            hbf, 1024, Wf1T, 1024, ffn1, 2048,
            barena + OFF_BF1 + l * 2 * D, 1024, 0, 0, 0, 0);
        // FFN2
        gemm_nt<false, false><<<dim3(24, 8, 1), 256, 0, stream>>>(
            ffn1, 2048, Wf2T, 2048, tmpbf, 1024,
            barena + OFF_BF2 + l * D, 2048, 0, 0, 0, 0);
        ln_kernel<<<3072, 256, 0, stream>>>(h, tmpbf, hbf, barena + OFF_G2 + l * D, barena + OFF_B2N + l * D);
    }
    head_kernel<<<out_size, 256, 0, stream>>>(flag, h, barena, nePtr, naPtr, d_out);
}